// Round 1
// baseline (673.557 us; speedup 1.0000x reference)
//
#include <hip/hip_runtime.h>
#include <math.h>

// Problem constants: b=4,n=2048 -> 8192 rows; d=1024; h=8; e=16; cs=2048.
// Output: int32 indices [8192, 8].
//
// Reformulation (exact w.r.t. argmax):
//   argmax_c q.cbn_c == argmax_c ((x.W - mu*colsum(W)) . cbn_c)
// since LN's 1/sigma and q's 1/||proj|| are positive per-(row,head) constants
// that cancel across c. Only the codebook must be L2-normalized (done in fp64
// then rounded once to fp32 - at least as accurate as the reference path).

// ---- async global->LDS staging: each lane contributes 16B, lands at
// ldsbase + lane*16 (wave-uniform base, guide m97/m104) ----
__device__ __forceinline__ void stage16(const float* g, float* lds_base) {
  __builtin_amdgcn_global_load_lds(
      (const __attribute__((address_space(1))) void*)g,
      (__attribute__((address_space(3))) void*)lds_base, 16, 0, 0);
}

// ---------------- K1: normalize codebook (fp64 internally) ----------------
__global__ __launch_bounds__(256) void k_cbnorm(const float* __restrict__ cb,
                                                float* __restrict__ cbn) {
  int v = blockIdx.x * 256 + threadIdx.x;      // 0..16383 vectors of 16
  const float4* p = (const float4*)(cb + (size_t)v * 16);
  float4 q0 = p[0], q1 = p[1], q2 = p[2], q3 = p[3];
  float f[16] = {q0.x,q0.y,q0.z,q0.w, q1.x,q1.y,q1.z,q1.w,
                 q2.x,q2.y,q2.z,q2.w, q3.x,q3.y,q3.z,q3.w};
  double s = 0.0;
#pragma unroll
  for (int i = 0; i < 16; ++i) s += (double)f[i] * (double)f[i];
  double inv = 1.0 / sqrt(s + 1e-12);
  float r[16];
#pragma unroll
  for (int i = 0; i < 16; ++i) r[i] = (float)((double)f[i] * inv);
  float4* o = (float4*)(cbn + (size_t)v * 16);
  float4* rr = (float4*)r;
  o[0] = rr[0]; o[1] = rr[1]; o[2] = rr[2]; o[3] = rr[3];
}

// ---------------- K2: column sums of W (for the mu correction) -------------
__global__ __launch_bounds__(256) void k_colsum(const float* __restrict__ W,
                                                float* __restrict__ cs) {
  __shared__ float red[16][17];
  int h = blockIdx.x;                      // 0..7
  int e = threadIdx.x & 15, part = threadIdx.x >> 4;   // 16 parts of 64 d's
  const float* base = W + h * 16384 + e;
  float s = 0.f;
  int d0 = part * 64;
  for (int i = 0; i < 64; ++i) s += base[(d0 + i) * 16];
  red[e][part] = s;
  __syncthreads();
  if (threadIdx.x < 16) {
    float t = 0.f;
#pragma unroll
    for (int p = 0; p < 16; ++p) t += red[threadIdx.x][p];
    cs[h * 16 + threadIdx.x] = t;
  }
}

// ---------------- K3: fused mean + projection GEMM -------------------------
// 512 blocks x 256 threads; block = 16 rows, all 128 cols; K chunked by 64.
// Thread (t): rows 4*(t/64)+j (wave-uniform -> LDS broadcast reads),
//             cols {t%64, t%64+64}. 8 accumulators.
// sW layout [h][1040] (pad: 1040%32==16 -> 2-way bank alias == free).
__global__ __launch_bounds__(256) void k_proj(const float* __restrict__ x,
                                              const float* __restrict__ W,
                                              const float* __restrict__ csum,
                                              float* __restrict__ tmat) {
  __shared__ __align__(16) float sW[8 * 1040];
  __shared__ __align__(16) float sX[16 * 64];
  __shared__ float sRS[16][17];
  __shared__ float sMu[16];
  const int t = threadIdx.x;
  const int lane = t & 63;
  const int w = t >> 6;                    // wave 0..3
  const int r0 = blockIdx.x * 16;
  const int c0 = lane;                     // cols c0 and c0+64
  const int b0 = (c0 >> 4) * 1040 + (c0 & 15);
  const int b1 = b0 + 4 * 1040;
  const int xr = t >> 4;                   // psum row
  const int xc = (t & 15) * 4;
  const int srow = r0 + 4 * w + (lane >> 4);   // x staging row for this lane
  const int scol = (lane & 15) * 4;

  float acc[4][2] = {{0,0},{0,0},{0,0},{0,0}};
  float psum = 0.f;

  for (int ch = 0; ch < 16; ++ch) {
    const int dc = ch * 64;
    __syncthreads();                       // protect previous iter's reads
    // x chunk: 16 rows x 64 -> one wave-load per wave (4 rows each)
    stage16(x + (size_t)srow * 1024 + dc + scol, sX + w * 256);
    // W chunk: per head 1024 contiguous floats = 4 wave-loads; wave w does h=w,w+4
#pragma unroll
    for (int q = 0; q < 2; ++q) {
      const int hh = w + 4 * q;
      const float* gw = W + hh * 16384 + dc * 16;
      float* lb = sW + hh * 1040;
#pragma unroll
      for (int s2 = 0; s2 < 4; ++s2)
        stage16(gw + s2 * 256 + lane * 4, lb + s2 * 256);
    }
    __syncthreads();
    {  // row-sum partials for mu (each element counted once per chunk)
      float4 v = *(const float4*)(sX + xr * 64 + xc);
      psum += (v.x + v.y) + (v.z + v.w);
    }
    // chunk-local accumulators (shorter fp32 error random walk)
    float ca[4][2] = {{0,0},{0,0},{0,0},{0,0}};
#pragma unroll
    for (int dk = 0; dk < 64; ++dk) {
      float w0 = sW[b0 + dk * 16];
      float w1 = sW[b1 + dk * 16];
#pragma unroll
      for (int j = 0; j < 4; ++j) {
        float xv = sX[(4 * w + j) * 64 + dk];   // broadcast
        ca[j][0] += xv * w0;
        ca[j][1] += xv * w1;
      }
    }
#pragma unroll
    for (int j = 0; j < 4; ++j) { acc[j][0] += ca[j][0]; acc[j][1] += ca[j][1]; }
  }

  sRS[xr][t & 15] = psum;
  __syncthreads();
  if (t < 16) {
    float s = 0.f;
#pragma unroll
    for (int m = 0; m < 16; ++m) s += sRS[t][m];
    sMu[t] = s * (1.0f / 1024.0f);
  }
  __syncthreads();
  float cs0 = csum[c0], cs1 = csum[c0 + 64];
#pragma unroll
  for (int j = 0; j < 4; ++j) {
    int r = 4 * w + j;
    float m = sMu[r];
    tmat[(size_t)(r0 + r) * 128 + c0]      = acc[j][0] - m * cs0;
    tmat[(size_t)(r0 + r) * 128 + c0 + 64] = acc[j][1] - m * cs1;
  }
}

// ---------------- K4: argmax over codes -----------------------------------
// Grid (512 rowgroups, 8 heads) x 256 threads. Block = (head, 16 rows).
// Thread holds 4 code vectors in regs per batch (2 batches), streams 16 rows
// from LDS (broadcast b128). Tie-break = lowest code index (matches argmax).
__global__ __launch_bounds__(256) void k_argmax(const float* __restrict__ tmat,
                                                const float* __restrict__ cbn,
                                                int* __restrict__ out) {
  __shared__ __align__(16) float pt[16][16];
  __shared__ float sval[16][257];
  __shared__ int   sidx[16][257];
  __shared__ float s2v[16][17];
  __shared__ int   s2i[16][17];
  const int t = threadIdx.x;
  const int h = blockIdx.y;
  const int r0 = blockIdx.x * 16;
  pt[t >> 4][t & 15] = tmat[(size_t)(r0 + (t >> 4)) * 128 + h * 16 + (t & 15)];
  __syncthreads();

  float best[16];
  int   bidx[16];
#pragma unroll
  for (int r = 0; r < 16; ++r) { best[r] = -3.402823466e38f; bidx[r] = 0; }
  const float* cbh = cbn + (size_t)h * 2048 * 16;

  for (int b = 0; b < 2; ++b) {
    float cbv[4][16];
#pragma unroll
    for (int i = 0; i < 4; ++i) {
      int c = b * 1024 + i * 256 + t;
      const float4* p = (const float4*)(cbh + (size_t)c * 16);
      float4 q0 = p[0], q1 = p[1], q2 = p[2], q3 = p[3];
      cbv[i][0]=q0.x; cbv[i][1]=q0.y; cbv[i][2]=q0.z; cbv[i][3]=q0.w;
      cbv[i][4]=q1.x; cbv[i][5]=q1.y; cbv[i][6]=q1.z; cbv[i][7]=q1.w;
      cbv[i][8]=q2.x; cbv[i][9]=q2.y; cbv[i][10]=q2.z; cbv[i][11]=q2.w;
      cbv[i][12]=q3.x; cbv[i][13]=q3.y; cbv[i][14]=q3.z; cbv[i][15]=q3.w;
    }
#pragma unroll
    for (int r = 0; r < 16; ++r) {
      const float4* pp = (const float4*)&pt[r][0];
      float4 a0 = pp[0], a1 = pp[1], a2 = pp[2], a3 = pp[3];
      float pr[16] = {a0.x,a0.y,a0.z,a0.w, a1.x,a1.y,a1.z,a1.w,
                      a2.x,a2.y,a2.z,a2.w, a3.x,a3.y,a3.z,a3.w};
#pragma unroll
      for (int i = 0; i < 4; ++i) {
        float s = 0.f;
#pragma unroll
        for (int e = 0; e < 16; ++e) s += cbv[i][e] * pr[e];
        int c = b * 1024 + i * 256 + t;     // per-lane codes ascend -> strict >
        if (s > best[r]) { best[r] = s; bidx[r] = c; }
      }
    }
  }

#pragma unroll
  for (int r = 0; r < 16; ++r) { sval[r][t] = best[r]; sidx[r][t] = bidx[r]; }
  __syncthreads();
  {
    const int rr = t & 15, seg = t >> 4;    // (r = t&15) keeps reads ~conflict-free
    float bv = -3.402823466e38f; int bi = 0;
    for (int k = 0; k < 16; ++k) {
      float v = sval[rr][seg * 16 + k]; int ix = sidx[rr][seg * 16 + k];
      if (v > bv || (v == bv && ix < bi)) { bv = v; bi = ix; }
    }
    s2v[rr][seg] = bv; s2i[rr][seg] = bi;
  }
  __syncthreads();
  if (t < 16) {
    float bv = -3.402823466e38f; int bi = 0;
#pragma unroll
    for (int k = 0; k < 16; ++k) {
      float v = s2v[t][k]; int ix = s2i[t][k];
      if (v > bv || (v == bv && ix < bi)) { bv = v; bi = ix; }
    }
    out[(size_t)(r0 + t) * 8 + h] = bi;
  }
}

extern "C" void kernel_launch(void* const* d_in, const int* in_sizes, int n_in,
                              void* d_out, int out_size, void* d_ws, size_t ws_size,
                              hipStream_t stream) {
  (void)in_sizes; (void)n_in; (void)out_size; (void)ws_size;
  const float* x  = (const float*)d_in[0];   // [4,2048,1024]
  const float* rp = (const float*)d_in[1];   // [8,1024,16]
  const float* cb = (const float*)d_in[2];   // [8,2048,16]
  int* out = (int*)d_out;                    // [8192,8] int32

  float* ws   = (float*)d_ws;
  float* cbn  = ws;                          // 262144 floats (1 MB)
  float* csum = ws + 262144;                 // 128 floats
  float* tmat = ws + 262144 + 128;           // 1048576 floats (4 MB), 16B-aligned

  hipLaunchKernelGGL(k_cbnorm, dim3(64),       dim3(256), 0, stream, cb, cbn);
  hipLaunchKernelGGL(k_colsum, dim3(8),        dim3(256), 0, stream, rp, csum);
  hipLaunchKernelGGL(k_proj,   dim3(512),      dim3(256), 0, stream, x, rp, csum, tmat);
  hipLaunchKernelGGL(k_argmax, dim3(512, 8),   dim3(256), 0, stream, tmat, cbn, out);
}

// Round 2
// 236.750 us; speedup vs baseline: 2.8450x; 2.8450x over previous
//
#include <hip/hip_runtime.h>
#include <math.h>

// Problem constants: b=4,n=2048 -> 8192 rows; d=1024; h=8; e=16; cs=2048.
// Output: int32 indices [8192, 8].
//
// Reformulation (exact w.r.t. argmax):
//   argmax_c q.cbn_c == argmax_c ((x.W - mu*colsum(W)) . cbn_c)
// since LN's 1/sigma and q's 1/||proj|| are positive per-(row,head) constants
// that cancel across c. Only the codebook must be L2-normalized (fp64).

__device__ __forceinline__ void stage16(const float* g, float* lds_base) {
  __builtin_amdgcn_global_load_lds(
      (const __attribute__((address_space(1))) void*)g,
      (__attribute__((address_space(3))) void*)lds_base, 16, 0, 0);
}

// ---------------- K1: normalize codebook (fp64 internally) ----------------
__global__ __launch_bounds__(256) void k_cbnorm(const float* __restrict__ cb,
                                                float* __restrict__ cbn) {
  int v = blockIdx.x * 256 + threadIdx.x;      // 0..16383 vectors of 16
  const float4* p = (const float4*)(cb + (size_t)v * 16);
  float4 q0 = p[0], q1 = p[1], q2 = p[2], q3 = p[3];
  float f[16] = {q0.x,q0.y,q0.z,q0.w, q1.x,q1.y,q1.z,q1.w,
                 q2.x,q2.y,q2.z,q2.w, q3.x,q3.y,q3.z,q3.w};
  double s = 0.0;
#pragma unroll
  for (int i = 0; i < 16; ++i) s += (double)f[i] * (double)f[i];
  double inv = 1.0 / sqrt(s + 1e-12);
  float r[16];
#pragma unroll
  for (int i = 0; i < 16; ++i) r[i] = (float)((double)f[i] * inv);
  float4* o = (float4*)(cbn + (size_t)v * 16);
  float4* rr = (float4*)r;
  o[0] = rr[0]; o[1] = rr[1]; o[2] = rr[2]; o[3] = rr[3];
}

// ---------------- K2: column sums of W (for the mu correction) -------------
__global__ __launch_bounds__(256) void k_colsum(const float* __restrict__ W,
                                                float* __restrict__ cs) {
  __shared__ float red[16][17];
  int h = blockIdx.x;                      // 0..7
  int e = threadIdx.x & 15, part = threadIdx.x >> 4;   // 16 parts of 64 d's
  const float* base = W + h * 16384 + e;
  float s = 0.f;
  int d0 = part * 64;
  for (int i = 0; i < 64; ++i) s += base[(d0 + i) * 16];
  red[e][part] = s;
  __syncthreads();
  if (threadIdx.x < 16) {
    float t = 0.f;
#pragma unroll
    for (int p = 0; p < 16; ++p) t += red[threadIdx.x][p];
    cs[h * 16 + threadIdx.x] = t;
  }
}

// ---------------- K3: fused mean + projection GEMM -------------------------
// 512 blocks x 256 threads; block = 16 rows, all 128 cols; K chunked by 64.
__global__ __launch_bounds__(256) void k_proj(const float* __restrict__ x,
                                              const float* __restrict__ W,
                                              const float* __restrict__ csum,
                                              float* __restrict__ tmat) {
  __shared__ __align__(16) float sW[8 * 1040];
  __shared__ __align__(16) float sX[16 * 64];
  __shared__ float sRS[16][17];
  __shared__ float sMu[16];
  const int t = threadIdx.x;
  const int lane = t & 63;
  const int w = t >> 6;                    // wave 0..3
  const int r0 = blockIdx.x * 16;
  const int c0 = lane;                     // cols c0 and c0+64
  const int b0 = (c0 >> 4) * 1040 + (c0 & 15);
  const int b1 = b0 + 4 * 1040;
  const int xr = t >> 4;                   // psum row
  const int xc = (t & 15) * 4;
  const int srow = r0 + 4 * w + (lane >> 4);   // x staging row for this lane
  const int scol = (lane & 15) * 4;

  float acc[4][2] = {{0,0},{0,0},{0,0},{0,0}};
  float psum = 0.f;

  for (int ch = 0; ch < 16; ++ch) {
    const int dc = ch * 64;
    __syncthreads();                       // protect previous iter's reads
    stage16(x + (size_t)srow * 1024 + dc + scol, sX + w * 256);
#pragma unroll
    for (int q = 0; q < 2; ++q) {
      const int hh = w + 4 * q;
      const float* gw = W + hh * 16384 + dc * 16;
      float* lb = sW + hh * 1040;
#pragma unroll
      for (int s2 = 0; s2 < 4; ++s2)
        stage16(gw + s2 * 256 + lane * 4, lb + s2 * 256);
    }
    __syncthreads();
    {  // row-sum partials for mu
      float4 v = *(const float4*)(sX + xr * 64 + xc);
      psum += (v.x + v.y) + (v.z + v.w);
    }
    float ca[4][2] = {{0,0},{0,0},{0,0},{0,0}};
#pragma unroll
    for (int dk = 0; dk < 64; ++dk) {
      float w0 = sW[b0 + dk * 16];
      float w1 = sW[b1 + dk * 16];
#pragma unroll
      for (int j = 0; j < 4; ++j) {
        float xv = sX[(4 * w + j) * 64 + dk];   // broadcast
        ca[j][0] += xv * w0;
        ca[j][1] += xv * w1;
      }
    }
#pragma unroll
    for (int j = 0; j < 4; ++j) { acc[j][0] += ca[j][0]; acc[j][1] += ca[j][1]; }
  }

  sRS[xr][t & 15] = psum;
  __syncthreads();
  if (t < 16) {
    float s = 0.f;
#pragma unroll
    for (int m = 0; m < 16; ++m) s += sRS[t][m];
    sMu[t] = s * (1.0f / 1024.0f);
  }
  __syncthreads();
  float cs0 = csum[c0], cs1 = csum[c0 + 64];
#pragma unroll
  for (int j = 0; j < 4; ++j) {
    int r = 4 * w + j;
    float m = sMu[r];
    tmat[(size_t)(r0 + r) * 128 + c0]      = acc[j][0] - m * cs0;
    tmat[(size_t)(r0 + r) * 128 + c0 + 64] = acc[j][1] - m * cs1;
  }
}

// ---------------- K4: argmax over codes (register-blocked, spill-free) -----
// Grid (64 rowgroups, 8 heads) x 256 threads. Block = (head, 128 rows).
// 16 code-tiles of 128. Thread tile: 8 rows x 8 codes (64 fp32 acc regs).
// rg = t>>4 (0..15), cg = t&15. Thread rows: j*16+rg; thread codes in tile:
// i*16+cg. Pitch-17 LDS => per-wave read addresses stride 17 (coprime 32)
// => conflict-free broadcasts. Per e-step: 16 ds_read_b32 (~93cyc) feeding
// 64 v_fmac (~128cyc) per wave => VALU-bound. Tie-break: per-thread code ids
// strictly ascend over (tile,i) with strict '>' => first max; cross-thread
// reduce compares (v,idx) lexicographically.
__global__ __launch_bounds__(256) void k_argmax(const float* __restrict__ tmat,
                                                const float* __restrict__ cbn,
                                                int* __restrict__ out) {
  __shared__ float sPt[128 * 17];
  __shared__ float sCb[128 * 17];
  __shared__ float sRv[128 * 16];
  __shared__ int   sRi[128 * 16];
  const int t = threadIdx.x;
  const int h = blockIdx.y;
  const int r0 = blockIdx.x * 128;
  const int rg = t >> 4;                   // 0..15
  const int cg = t & 15;                   // 0..15

  {  // stage 128 rows x 16 head-cols of tmat into padded LDS
    int r = t >> 1, hf = t & 1;
    const float* src = tmat + (size_t)(r0 + r) * 128 + h * 16 + hf * 8;
    float4 a = ((const float4*)src)[0];
    float4 b = ((const float4*)src)[1];
    float* d = sPt + r * 17 + hf * 8;
    d[0] = a.x; d[1] = a.y; d[2] = a.z; d[3] = a.w;
    d[4] = b.x; d[5] = b.y; d[6] = b.z; d[7] = b.w;
  }

  float best[8];
  int   bidx[8];
#pragma unroll
  for (int j = 0; j < 8; ++j) { best[j] = -3.402823466e38f; bidx[j] = 0; }
  const float* cbh = cbn + (size_t)h * 2048 * 16;

  for (int tile = 0; tile < 16; ++tile) {
    __syncthreads();                       // protect prev tile reads / sPt stage
    {  // stage 128 codes x 16 into padded LDS
      int c = t >> 1, hf = t & 1;
      const float* src = cbh + (size_t)(tile * 128 + c) * 16 + hf * 8;
      float4 a = ((const float4*)src)[0];
      float4 b = ((const float4*)src)[1];
      float* d = sCb + c * 17 + hf * 8;
      d[0] = a.x; d[1] = a.y; d[2] = a.z; d[3] = a.w;
      d[4] = b.x; d[5] = b.y; d[6] = b.z; d[7] = b.w;
    }
    __syncthreads();

    float acc[8][8];
#pragma unroll
    for (int j = 0; j < 8; ++j)
#pragma unroll
      for (int i = 0; i < 8; ++i) acc[j][i] = 0.f;

#pragma unroll
    for (int e = 0; e < 16; ++e) {
      float rowv[8], codev[8];
#pragma unroll
      for (int j = 0; j < 8; ++j) rowv[j] = sPt[(j * 16 + rg) * 17 + e];
#pragma unroll
      for (int i = 0; i < 8; ++i) codev[i] = sCb[(i * 16 + cg) * 17 + e];
#pragma unroll
      for (int j = 0; j < 8; ++j)
#pragma unroll
        for (int i = 0; i < 8; ++i) acc[j][i] += rowv[j] * codev[i];
    }

    const int cbase = tile * 128 + cg;
#pragma unroll
    for (int j = 0; j < 8; ++j)
#pragma unroll
      for (int i = 0; i < 8; ++i) {
        float v = acc[j][i];
        if (v > best[j]) { best[j] = v; bidx[j] = cbase + i * 16; }
      }
  }

  __syncthreads();
#pragma unroll
  for (int j = 0; j < 8; ++j) {
    sRv[(j * 16 + rg) * 16 + cg] = best[j];
    sRi[(j * 16 + rg) * 16 + cg] = bidx[j];
  }
  __syncthreads();
  if (t < 128) {
    float bv = -3.402823466e38f; int bi = 0x7fffffff;
#pragma unroll
    for (int k = 0; k < 16; ++k) {
      float v = sRv[t * 16 + k]; int ix = sRi[t * 16 + k];
      if (v > bv || (v == bv && ix < bi)) { bv = v; bi = ix; }
    }
    out[(size_t)(r0 + t) * 8 + h] = bi;
  }
}

extern "C" void kernel_launch(void* const* d_in, const int* in_sizes, int n_in,
                              void* d_out, int out_size, void* d_ws, size_t ws_size,
                              hipStream_t stream) {
  (void)in_sizes; (void)n_in; (void)out_size; (void)ws_size;
  const float* x  = (const float*)d_in[0];   // [4,2048,1024]
  const float* rp = (const float*)d_in[1];   // [8,1024,16]
  const float* cb = (const float*)d_in[2];   // [8,2048,16]
  int* out = (int*)d_out;                    // [8192,8] int32

  float* ws   = (float*)d_ws;
  float* cbn  = ws;                          // 262144 floats (1 MB)
  float* csum = ws + 262144;                 // 128 floats
  float* tmat = ws + 262144 + 128;           // 1048576 floats (4 MB)

  hipLaunchKernelGGL(k_cbnorm, dim3(64),     dim3(256), 0, stream, cb, cbn);
  hipLaunchKernelGGL(k_colsum, dim3(8),      dim3(256), 0, stream, rp, csum);
  hipLaunchKernelGGL(k_proj,   dim3(512),    dim3(256), 0, stream, x, rp, csum, tmat);
  hipLaunchKernelGGL(k_argmax, dim3(64, 8),  dim3(256), 0, stream, tmat, cbn, out);
}

// Round 3
// 211.344 us; speedup vs baseline: 3.1870x; 1.1202x over previous
//
#include <hip/hip_runtime.h>
#include <math.h>

// b=4,n=2048 -> 8192 rows; d=1024; h=8; e=16; cs=2048. Output int32 [8192,8].
// argmax_c q.cbn_c == argmax_c ((x.W - mu*colsum(W)) . cbn_c): LN 1/sigma and
// q-norm are positive per-(row,head) scalars -> cancel. Codebook normalized fp64.

__device__ __forceinline__ void stage16(const float* g, float* lds_base) {
  __builtin_amdgcn_global_load_lds(
      (const __attribute__((address_space(1))) void*)g,
      (__attribute__((address_space(3))) void*)lds_base, 16, 0, 0);
}

// ---------------- K1: normalize codebook (fp64 internally) ----------------
__global__ __launch_bounds__(256) void k_cbnorm(const float* __restrict__ cb,
                                                float* __restrict__ cbn) {
  int v = blockIdx.x * 256 + threadIdx.x;
  const float4* p = (const float4*)(cb + (size_t)v * 16);
  float4 q0 = p[0], q1 = p[1], q2 = p[2], q3 = p[3];
  float f[16] = {q0.x,q0.y,q0.z,q0.w, q1.x,q1.y,q1.z,q1.w,
                 q2.x,q2.y,q2.z,q2.w, q3.x,q3.y,q3.z,q3.w};
  double s = 0.0;
#pragma unroll
  for (int i = 0; i < 16; ++i) s += (double)f[i] * (double)f[i];
  double inv = 1.0 / sqrt(s + 1e-12);
  float r[16];
#pragma unroll
  for (int i = 0; i < 16; ++i) r[i] = (float)((double)f[i] * inv);
  float4* o = (float4*)(cbn + (size_t)v * 16);
  float4* rr = (float4*)r;
  o[0] = rr[0]; o[1] = rr[1]; o[2] = rr[2]; o[3] = rr[3];
}

// ---------------- K2: column sums of W --------------------------------------
__global__ __launch_bounds__(256) void k_colsum(const float* __restrict__ W,
                                                float* __restrict__ cs) {
  __shared__ float red[16][17];
  int h = blockIdx.x;
  int e = threadIdx.x & 15, part = threadIdx.x >> 4;
  const float* base = W + h * 16384 + e;
  float s = 0.f;
  int d0 = part * 64;
  for (int i = 0; i < 64; ++i) s += base[(d0 + i) * 16];
  red[e][part] = s;
  __syncthreads();
  if (threadIdx.x < 16) {
    float t = 0.f;
#pragma unroll
    for (int p = 0; p < 16; ++p) t += red[threadIdx.x][p];
    cs[h * 16 + threadIdx.x] = t;
  }
}

// ---------------- K2b: row means of x (memory-bound) ------------------------
__global__ __launch_bounds__(256) void k_mu(const float* __restrict__ x,
                                            float* __restrict__ mu) {
  __shared__ float red[16][17];
  const int t = threadIdx.x;
  const int g = t & 15, tg = t >> 4;
  const int row = blockIdx.x * 16 + tg;
  const float4* xr = (const float4*)(x + (size_t)row * 1024);
  float s = 0.f;
#pragma unroll
  for (int m = 0; m < 16; ++m) {
    float4 v = xr[g + 16 * m];
    s += (v.x + v.y) + (v.z + v.w);
  }
  red[tg][g] = s;
  __syncthreads();
  if (g == 0) {
    float tt = 0.f;
#pragma unroll
    for (int k = 0; k < 16; ++k) tt += red[tg][k];
    mu[row] = tt * (1.0f / 1024.0f);
  }
}

// ---------------- K3: projection GEMM partials (K-split 2) ------------------
// Grid (256 rowgroups, 2 ksplit) x 256. Block: 32 rows x 128 cols x K=512.
// sX [32 rows][64 k] (b128 row reads over k, 2-addr broadcast = free).
// sW [64 k][132 cols] k-major (col reads b32: 32 distinct banks = free).
// Thread (rg=t>>5, cg=t&31): rows rg*4+j, cols cg+32i -> 16 acc.
__global__ __launch_bounds__(256) void k_proj(const float* __restrict__ x,
                                              const float* __restrict__ W,
                                              float* __restrict__ part) {
  __shared__ __align__(16) float sX[32 * 64];
  __shared__ __align__(16) float sW[64 * 132];
  const int t = threadIdx.x;
  const int lane = t & 63, w = t >> 6;
  const int r0 = blockIdx.x * 32;
  const int ks = blockIdx.y;
  const int koff = ks * 512;
  const int rg = t >> 5, cg = t & 31;
  const int srow = 8 * w + (lane >> 4);      // +4s
  const int scol = (lane & 15) * 4;
  const int wk = t >> 2;                     // W stage: k index
  const int we = (t & 3) * 4;                // e offset

  float acc[4][4];
#pragma unroll
  for (int j = 0; j < 4; ++j)
#pragma unroll
    for (int i = 0; i < 4; ++i) acc[j][i] = 0.f;

  for (int ch = 0; ch < 8; ++ch) {
    const int dc = ch * 64;
    __syncthreads();
    // sX: 32 rows x 64 k via global_load_lds (base wave-uniform, lane*16B)
    stage16(x + (size_t)(r0 + srow) * 1024 + koff + dc + scol,
            sX + (8 * w) * 64);
    stage16(x + (size_t)(r0 + srow + 4) * 1024 + koff + dc + scol,
            sX + (8 * w + 4) * 64);
    // sW: transpose-stage [k][col]: per h one float4 load + ds_write_b128
#pragma unroll
    for (int h = 0; h < 8; ++h) {
      float4 gv = *(const float4*)(W + (size_t)h * 16384 + (koff + dc) * 16 + 4 * t);
      *(float4*)(sW + wk * 132 + h * 16 + we) = gv;
    }
    __syncthreads();
#pragma unroll
    for (int kc = 0; kc < 16; ++kc) {
      float4 rv[4];
#pragma unroll
      for (int j = 0; j < 4; ++j)
        rv[j] = *(const float4*)(sX + (rg * 4 + j) * 64 + kc * 4);
#pragma unroll
      for (int kk = 0; kk < 4; ++kk) {
        float cv[4];
#pragma unroll
        for (int i = 0; i < 4; ++i) cv[i] = sW[(kc * 4 + kk) * 132 + cg + 32 * i];
#pragma unroll
        for (int j = 0; j < 4; ++j) {
          float xv = (kk == 0) ? rv[j].x : (kk == 1) ? rv[j].y
                   : (kk == 2) ? rv[j].z : rv[j].w;
#pragma unroll
          for (int i = 0; i < 4; ++i) acc[j][i] += xv * cv[i];
        }
      }
    }
  }
  float* po = part + ((size_t)ks * 8192 + r0) * 128;
#pragma unroll
  for (int j = 0; j < 4; ++j)
#pragma unroll
    for (int i = 0; i < 4; ++i)
      po[(size_t)(rg * 4 + j) * 128 + cg + 32 * i] = acc[j][i];
}

// ---------------- K3b: combine halves - mu*colsum ---------------------------
__global__ __launch_bounds__(256) void k_combine(const float* __restrict__ part,
                                                 const float* __restrict__ mu,
                                                 const float* __restrict__ csum,
                                                 float* __restrict__ tmat) {
  int idx = blockIdx.x * 256 + threadIdx.x;   // float4 index, 262144 total
  int row = idx >> 5, c4 = (idx & 31) * 4;
  float4 p0 = *(const float4*)(part + (size_t)row * 128 + c4);
  float4 p1 = *(const float4*)(part + (size_t)(8192 + row) * 128 + c4);
  float4 cs = *(const float4*)(csum + c4);
  float m = mu[row];
  float4 o;
  o.x = p0.x + p1.x - m * cs.x;
  o.y = p0.y + p1.y - m * cs.y;
  o.z = p0.z + p1.z - m * cs.z;
  o.w = p0.w + p1.w - m * cs.w;
  *(float4*)(tmat + (size_t)row * 128 + c4) = o;
}

// ---------------- K4: argmax partials (code-half split) ---------------------
// Grid (64 rowgroups, 8 heads, 2 halves) x 256 = 1024 blocks (4/CU).
// Block: 128 rows x 1024 codes (8 tiles of 128). Thread (rg=t>>4,cg=t&15):
// rows j*16+rg, codes i*16+cg -> 8x8 acc. LDS e-chunk-major float4 [ec][128]:
// row reads 4 addrs on 4 distinct bank-groups (broadcast, free); code reads
// 2-way alias (free). All LDS traffic is b128.
__global__ __launch_bounds__(256) void k_argmax(const float* __restrict__ tmat,
                                                const float* __restrict__ cbn,
                                                float* __restrict__ amv,
                                                int* __restrict__ ami) {
  __shared__ __align__(16) float sPt[4 * 128 * 4];   // [ec][r] float4
  __shared__ __align__(16) float sCb[4 * 128 * 4];   // [ec][c] float4
  __shared__ float sRv[128 * 17];
  __shared__ int   sRi[128 * 17];
  const int t = threadIdx.x;
  const int h = blockIdx.y;
  const int half = blockIdx.z;
  const int r0 = blockIdx.x * 128;
  const int rg = t >> 4, cg = t & 15;

  {  // stage 128 rows x 16 e of tmat, e-chunk-major
    int r = t >> 1, hf = t & 1;
    const float* src = tmat + (size_t)(r0 + r) * 128 + h * 16 + hf * 8;
    float4 a = ((const float4*)src)[0];
    float4 b = ((const float4*)src)[1];
    ((float4*)sPt)[(2 * hf) * 128 + r] = a;
    ((float4*)sPt)[(2 * hf + 1) * 128 + r] = b;
  }

  float best[8];
  int   bidx[8];
#pragma unroll
  for (int j = 0; j < 8; ++j) { best[j] = -3.402823466e38f; bidx[j] = 0; }
  const float* cbh = cbn + ((size_t)h * 2048 + half * 1024) * 16;

  for (int tile = 0; tile < 8; ++tile) {
    __syncthreads();
    {  // stage 128 codes x 16 e, e-chunk-major
      int c = t >> 1, hf = t & 1;
      const float* src = cbh + (size_t)(tile * 128 + c) * 16 + hf * 8;
      float4 a = ((const float4*)src)[0];
      float4 b = ((const float4*)src)[1];
      ((float4*)sCb)[(2 * hf) * 128 + c] = a;
      ((float4*)sCb)[(2 * hf + 1) * 128 + c] = b;
    }
    __syncthreads();

    float acc[8][8];
#pragma unroll
    for (int j = 0; j < 8; ++j)
#pragma unroll
      for (int i = 0; i < 8; ++i) acc[j][i] = 0.f;

#pragma unroll
    for (int ec = 0; ec < 4; ++ec) {
      float4 rv[8];
#pragma unroll
      for (int j = 0; j < 8; ++j)
        rv[j] = ((const float4*)sPt)[ec * 128 + j * 16 + rg];
#pragma unroll
      for (int i = 0; i < 8; ++i) {
        float4 cv = ((const float4*)sCb)[ec * 128 + i * 16 + cg];
#pragma unroll
        for (int j = 0; j < 8; ++j)
          acc[j][i] += rv[j].x * cv.x + rv[j].y * cv.y +
                       rv[j].z * cv.z + rv[j].w * cv.w;
      }
    }

    const int cb0 = half * 1024 + tile * 128 + cg;
#pragma unroll
    for (int j = 0; j < 8; ++j)
#pragma unroll
      for (int i = 0; i < 8; ++i) {
        float v = acc[j][i];
        if (v > best[j]) { best[j] = v; bidx[j] = cb0 + i * 16; }
      }
  }

  __syncthreads();
#pragma unroll
  for (int j = 0; j < 8; ++j) {
    sRv[(j * 16 + rg) * 17 + cg] = best[j];
    sRi[(j * 16 + rg) * 17 + cg] = bidx[j];
  }
  __syncthreads();
  if (t < 128) {
    float bv = -3.402823466e38f; int bi = 0x7fffffff;
#pragma unroll
    for (int k = 0; k < 16; ++k) {
      float v = sRv[t * 17 + k]; int ix = sRi[t * 17 + k];
      if (v > bv || (v == bv && ix < bi)) { bv = v; bi = ix; }
    }
    size_t o = ((size_t)half * 8192 + r0 + t) * 8 + h;
    amv[o] = bv; ami[o] = bi;
  }
}

// ---------------- K5: merge the two code-halves -----------------------------
__global__ __launch_bounds__(256) void k_amred(const float* __restrict__ amv,
                                               const int* __restrict__ ami,
                                               int* __restrict__ out) {
  int i = blockIdx.x * 256 + threadIdx.x;   // 65536
  float v0 = amv[i], v1 = amv[65536 + i];
  int i0 = ami[i], i1 = ami[65536 + i];
  out[i] = (v1 > v0) ? i1 : i0;             // tie -> half0 (lower idx) = first max
}

extern "C" void kernel_launch(void* const* d_in, const int* in_sizes, int n_in,
                              void* d_out, int out_size, void* d_ws, size_t ws_size,
                              hipStream_t stream) {
  (void)in_sizes; (void)n_in; (void)out_size; (void)ws_size;
  const float* x  = (const float*)d_in[0];   // [4,2048,1024]
  const float* rp = (const float*)d_in[1];   // [8,1024,16]
  const float* cb = (const float*)d_in[2];   // [8,2048,16]
  int* out = (int*)d_out;                    // [8192,8] int32

  float* ws   = (float*)d_ws;
  float* cbn  = ws;                          // [0, 262144)
  float* csum = ws + 262144;                 // 128
  float* mu   = ws + 262272;                 // 8192
  float* part = ws + 270464;                 // 2*8192*128 = 2097152
  float* tmat = ws + 2367616;                // 1048576
  float* amv  = ws + 3416192;                // 2*8192*8 = 131072
  int*   ami  = (int*)(ws + 3547264);        // 131072  (total ~14.7 MB)

  hipLaunchKernelGGL(k_cbnorm,  dim3(64),        dim3(256), 0, stream, cb, cbn);
  hipLaunchKernelGGL(k_colsum,  dim3(8),         dim3(256), 0, stream, rp, csum);
  hipLaunchKernelGGL(k_mu,      dim3(512),       dim3(256), 0, stream, x, mu);
  hipLaunchKernelGGL(k_proj,    dim3(256, 2),    dim3(256), 0, stream, x, rp, part);
  hipLaunchKernelGGL(k_combine, dim3(1024),      dim3(256), 0, stream, part, mu, csum, tmat);
  hipLaunchKernelGGL(k_argmax,  dim3(64, 8, 2),  dim3(256), 0, stream, tmat, cbn, amv, ami);
  hipLaunchKernelGGL(k_amred,   dim3(256),       dim3(256), 0, stream, amv, ami, out);
}